// Round 15
// baseline (252.004 us; speedup 1.0000x reference)
//
#include <hip/hip_runtime.h>
#include <math.h>

#define NPAIR 131072          // 8192 freqs x 16 channels
#define STEPS 19
#define VMD_BLOCKS 256        // x 512 threads = NPAIR
#define ND_BANKS 16

// XOR swizzle: spreads strided radix-8 writes across banks; keeps contiguous free
#define SW(a) ((a) ^ (((a) >> 5) & 31))

#define LD_RLX(p)    __hip_atomic_load((p),       __ATOMIC_RELAXED, __HIP_MEMORY_SCOPE_AGENT)
#define ST_RLX(p,v)  __hip_atomic_store((p),(v),  __ATOMIC_RELAXED, __HIP_MEMORY_SCOPE_AGENT)
#define FAA_RLX(p,v) __hip_atomic_fetch_add((p),(v),__ATOMIC_RELAXED, __HIP_MEMORY_SCOPE_AGENT)

// D-region layout (doubles) — R31 FIX: gbar needs int indices up to 800 =
// 3204 B ≈ 401 dbl per barrier region. R30 gave CNT2 only 104 dbl and memset
// stopped short -> CD-barrier root/flags in garbage -> deadlock (R24-class bug).
//   NDB[19][256] = [0,4864) | CNT  [4864,5400)  (536 dbl >= 529 needed, vmd barrier)
//   OHIST[18][8]   [5400,5544) | CNT2 [5544,5952) (408 dbl >= 401, cd barrier)
// hipMemsetAsync zeroes [0,5952); OHIST is store-only (overwritten before read).
// R28 LESSON: bulk arrays must NOT move through per-element agent-scope atomics
// (op-rate-bound at LLC, +22us for 6MB). Intra-kernel bulk visibility = normal
// cached stores + ONE __threadfence (wb) + barrier + ONE __threadfence (inv).
// R29/R30 LESSON: each kernel boundary costs ~15-20us; non-vmd kernel work is
// only ~20us — fusing kernels is the lever, fences are the tool.
#define D_NDB   0
#define D_CNT   4864
#define D_OHIST 5400
#define D_CNT2  5544
#define D_ZERO  5952

__device__ __forceinline__ float2 cadd(float2 a, float2 b){ return make_float2(a.x+b.x, a.y+b.y); }
__device__ __forceinline__ float2 csub(float2 a, float2 b){ return make_float2(a.x-b.x, a.y-b.y); }
__device__ __forceinline__ float2 cmul(float2 a, float2 b){
    return make_float2(a.x*b.x - a.y*b.y, a.x*b.y + a.y*b.x);
}
template<int SGN>
__device__ __forceinline__ float2 imul(float2 a){   // multiply by e^{SGN*i*pi/2}
    return (SGN > 0) ? make_float2(-a.y, a.x) : make_float2(a.y, -a.x);
}

// 8-point DFT: y_k = sum_r a_r e^{SGN*2pi i r k/8}
template<int SGN>
__device__ __forceinline__ void dft8(const float2* a, float2* y){
    const float C = 0.70710678118654752f;
    const float sg = (SGN > 0) ? 1.f : -1.f;
    float2 t0 = cadd(a[0], a[4]), t1 = csub(a[0], a[4]);
    float2 t2 = cadd(a[2], a[6]), t3 = imul<SGN>(csub(a[2], a[6]));
    float2 E0 = cadd(t0, t2), E2 = csub(t0, t2), E1 = cadd(t1, t3), E3 = csub(t1, t3);
    float2 s0 = cadd(a[1], a[5]), s1 = csub(a[1], a[5]);
    float2 s2 = cadd(a[3], a[7]), s3 = imul<SGN>(csub(a[3], a[7]));
    float2 O0 = cadd(s0, s2), O2 = csub(s0, s2), O1 = cadd(s1, s3), O3 = csub(s1, s3);
    float2 w1 = make_float2(C, sg * C), w3 = make_float2(-C, sg * C);
    float2 R0 = O0, R1 = cmul(O1, w1), R2 = imul<SGN>(O2), R3 = cmul(O3, w3);
    y[0] = cadd(E0, R0); y[4] = csub(E0, R0);
    y[1] = cadd(E1, R1); y[5] = csub(E1, R1);
    y[2] = cadd(E2, R2); y[6] = csub(E2, R2);
    y[3] = cadd(E3, R3); y[7] = csub(E3, R3);
}

// ===== in-LDS 8192-pt Stockham FFT: 4 radix-8 passes + 1 radix-2, 1024 threads =====
template<int SGN>
__device__ void lds_fft8192_r8(float2* lds, int tid){
    #pragma unroll
    for (int pi = 0; pi < 4; pi++){
        int ls = 3 * pi;
        int s  = 1 << ls;
        int nn = 8192 >> ls;
        int q = tid & (s - 1);
        float2 a[8], y[8];
        #pragma unroll
        for (int r = 0; r < 8; r++) a[r] = lds[SW(tid + (r << 10))];
        __syncthreads();
        dft8<SGN>(a, y);
        int p = tid >> ls;
        float ang = (float)(2 * p) / (float)nn;
        float sn, cs;
        sincospif(SGN > 0 ? ang : -ang, &sn, &cs);   // w = e^{SGN*2pi i p/nn}
        float2 w = make_float2(cs, sn);
        float2 wk = make_float2(1.f, 0.f);
        int o = q + ((tid - q) << 3);                 // q + 8*s*p
        lds[SW(o)] = y[0];
        #pragma unroll
        for (int k = 1; k < 8; k++){
            wk = cmul(wk, w);
            lds[SW(o + (k << ls))] = cmul(y[k], wk);
        }
        __syncthreads();
    }
    #pragma unroll
    for (int w4 = 0; w4 < 4; w4++){                   // final radix-2, twiddle-free
        int idx = (w4 << 10) + tid;
        float2 a = lds[SW(idx)], b = lds[SW(idx + 4096)];
        lds[SW(idx)]        = cadd(a, b);
        lds[SW(idx + 4096)] = csub(a, b);
    }
    __syncthreads();
}

// ===== in-LDS 4096-pt Stockham FFT: exactly 4 radix-8 passes, 512 active threads ====
template<int SGN>
__device__ void lds_fft4096_r8(float2* lds, int tid){
    #pragma unroll
    for (int pi = 0; pi < 4; pi++){
        int ls = 3 * pi;
        int s  = 1 << ls;
        int nn = 4096 >> ls;
        float2 a[8], y[8];
        int q = tid & (s - 1);
        if (tid < 512){
            #pragma unroll
            for (int r = 0; r < 8; r++) a[r] = lds[SW(tid + (r << 9))];
        }
        __syncthreads();
        if (tid < 512){
            dft8<SGN>(a, y);
            int p = tid >> ls;
            float ang = (float)(2 * p) / (float)nn;
            float sn, cs;
            sincospif(SGN > 0 ? ang : -ang, &sn, &cs);
            float2 w = make_float2(cs, sn);
            float2 wk = make_float2(1.f, 0.f);
            int o = q + ((tid - q) << 3);
            lds[SW(o)] = y[0];
            #pragma unroll
            for (int k = 1; k < 8; k++){
                wk = cmul(wk, w);
                lds[SW(o + (k << ls))] = cmul(y[k], wk);
            }
        }
        __syncthreads();
    }
}

// ===== proven relaxed LLC barrier (R16..R26 recipe), parametrized =====
// FAA for arrival (detection free in return value), stores for release fan-out,
// single-word polls, <=16 readers per polled line, all relaxed AGENT scope.
// Group size 16; ngroups groups. Monotonic rounds; cnt zeroed by memset.
// Layout spans int indices [0, 576+32*ngroups) — region must be zeroed!
__device__ __forceinline__ void gbar(int* cnt, int grp, int round, int ngroups){
    int old = FAA_RLX(&cnt[grp * 32], 1);
    bool released = false;
    if (old == 16 * round - 1){          // group-last: bump root counter
        int rold = FAA_RLX(&cnt[512], 1);
        if (rold == ngroups * round - 1){// root-last: broadcast ALL group flags
            for (int g = 0; g < ngroups; g++)
                ST_RLX(&cnt[576 + g * 32], round);
            released = true;
        }
    }
    if (!released)
        while (LD_RLX(&cnt[576 + grp * 32]) < round)
            __builtin_amdgcn_s_sleep(1);
}

// ===== kernel 1 (R30/R31): fused stageA + 19-step VMD =====
// stageA (R26 4-way DIT): blocks 0-63 compute C[bb] = FFT4096 of x[4n+r4] with
// NORMAL cached stores; release __threadfence (wb -> C durable at LLC);
// barrier round 1; acquire __threadfence (inv); plain coalesced C loads.
// VMD: R17 reduce, R23 rcp, R25 banked-atomicAdd in-LLC aggregation, R27 f32.
__global__ __launch_bounds__(512, 2) void k_vmd_all(const float* __restrict__ sig,
                                                    float2* __restrict__ C,
                                                    float2* __restrict__ U,
                                                    double* __restrict__ D){
    extern __shared__ float2 lds[];      // 32KB: stageA FFT4096 scratch
    double* NDB   = D + D_NDB;
    int*    CNT   = (int*)(D + D_CNT);
    double* OHIST = D + D_OHIST;

    int tid = blockIdx.x * 512 + threadIdx.x;   // [0,NPAIR), tid = cw*8192+j
    int lane = threadIdx.x & 63, wv = threadIdx.x >> 6;
    int mybank = (blockIdx.x & (ND_BANKS - 1)) * 16;
    int grp = blockIdx.x >> 4;                  // 16 groups of 16 blocks

    // ---- fused stage A (blocks 0-63), normal cached stores ----
    if (blockIdx.x < 64){
        int bb = blockIdx.x;                 // bb = cw*4 + r4
        int cwa = bb >> 2, r4 = bb & 3;
        int cs = (cwa + 8) & 15;             // fftshift over channel axis
        const float* sp = sig + cs * 8192;
        #pragma unroll
        for (int i = 0; i < 8; i++){         // samples 4p+r4 of mirrored extension
            int p = i * 512 + threadIdx.x;
            int x = 4 * p + r4;
            int mx = (x < 4096) ? (4095 - x) : ((x < 12288) ? (x - 4096) : (20479 - x));
            lds[SW(p)] = make_float2(sp[mx], 0.f);
        }
        __syncthreads();
        lds_fft4096_r8<-1>(lds, threadIdx.x);
        float2* dst = C + (size_t)bb * 4096;
        #pragma unroll
        for (int i = 0; i < 8; i++){
            int j2 = i * 512 + threadIdx.x;
            dst[j2] = lds[SW(j2)];
        }
        __syncthreads();                     // all waves' stores issued
        __threadfence();                     // release: writeback -> durable at LLC
    }
    __syncthreads();                         // fences complete before arrival
    if (threadIdx.x == 0) gbar(CNT, grp, 1, 16);   // round 1: C published
    __syncthreads();
    __threadfence();                         // acquire: invalidate stale L1/L2
    __syncthreads();

    int j = tid & 8191;
    int cw = tid >> 13;
    float fr = (float)j / 16384.0f;          // exact (j < 8192, pow2 divide)
    // R26 4-way combine: F[j] = C0 + w*C1 + w^2*C2 + w^3*C3, w = e^{-i pi j/8192}
    const float2* Cb = C + (size_t)(cw * 4) * 4096;
    int m = j & 4095;
    float2 C0 = Cb[m], C1 = Cb[4096 + m], C2 = Cb[8192 + m], C3 = Cb[12288 + m];
    float s1, c1, s2, c2;
    sincospif(-(float)j / 8192.0f, &s1, &c1);
    sincospif(-(float)j / 4096.0f, &s2, &c2);
    float2 w1 = make_float2(c1, s1), w2 = make_float2(c2, s2), w3 = cmul(w1, w2);
    float2 fv = cadd(cadd(C0, cmul(w1, C1)), cadd(cmul(w2, C2), cmul(w3, C3)));
    float fx = fv.x, fy = fv.y;
    float urx[8], ury[8], om[8];
    #pragma unroll
    for (int k = 0; k < 8; k++){ urx[k] = 0.f; ury[k] = 0.f; om[k] = 0.0625f * (float)k; }
    __shared__ float  lred[8][16];
    __shared__ double ndls[256];
    __shared__ double om_s[8];

    for (int step = 0; step < STEPS; step++){
        if (step > 0){
            #pragma unroll
            for (int k = 0; k < 8; k++) om[k] = (float)om_s[k];  // replicate astype(c64)
        }
        float sx = 0.f, sy = 0.f;
        #pragma unroll
        for (int k = 1; k < 8; k++){ sx += urx[k]; sy += ury[k]; }
        float lx = 0.f, ly = 0.f, nloc[8], dloc[8];
        #pragma unroll
        for (int k = 0; k < 8; k++){
            if (k > 0){ sx += lx - urx[k]; sy += ly - ury[k]; }
            float d = fr - om[k];
            float den = 1.0f + 2000.0f * d * d;
            float rden = 1.0f / den;                  // R23: 1 div + 2 mul
            float nx = (fx - sx) * rden, ny = (fy - sy) * rden;
            urx[k] = nx; ury[k] = ny;
            lx = nx; ly = ny;
            float pw = nx * nx + ny * ny;
            nloc[k] = fr * pw; dloc[k] = pw;
        }
        // ---- multi-value butterfly reduce: 16 floats across 64 lanes, 17 shuffles ----
        float s8[8];
        {
            bool hi = (lane & 32) != 0;
            #pragma unroll
            for (int k = 0; k < 8; k++){
                float t = hi ? nloc[k] : dloc[k];           // what we give away
                float r = __shfl_xor(t, 32);
                s8[k] = (hi ? dloc[k] : nloc[k]) + r;       // what we keep
            }
        }
        float s4v[4];
        {
            bool hi = (lane & 16) != 0;
            #pragma unroll
            for (int k = 0; k < 4; k++){
                float t = hi ? s8[k] : s8[k + 4];
                float r = __shfl_xor(t, 16);
                s4v[k] = (hi ? s8[k + 4] : s8[k]) + r;
            }
        }
        float s2v[2];
        {
            bool hi = (lane & 8) != 0;
            #pragma unroll
            for (int k = 0; k < 2; k++){
                float t = hi ? s4v[k] : s4v[k + 2];
                float r = __shfl_xor(t, 8);
                s2v[k] = (hi ? s4v[k + 2] : s4v[k]) + r;
            }
        }
        float sv;
        {
            bool hi = (lane & 4) != 0;
            float t = hi ? s2v[0] : s2v[1];
            float r = __shfl_xor(t, 4);
            sv = (hi ? s2v[1] : s2v[0]) + r;
        }
        sv += __shfl_xor(sv, 2);
        sv += __shfl_xor(sv, 1);
        // lane l holds wave-total for idx = l>>2 (idx<8: n_idx, idx>=8: d_{idx-8})
        if ((lane & 3) == 0) lred[wv][lane >> 2] = sv;
        __syncthreads();
        if (threadIdx.x < 16){
            double sum = 0.0;
            #pragma unroll
            for (int w = 0; w < 8; w++) sum += (double)lred[w][threadIdx.x];
            atomicAdd(&NDB[step * 256 + mybank + threadIdx.x], sum);  // LLC f64 atomic
        }
        __syncthreads();      // all waves vmcnt-drained -> NDB adds COMPLETE at LLC
        if (step < STEPS - 1){
            if (threadIdx.x == 0) gbar(CNT, grp, step + 2, 16);   // rounds 2..19
            __syncthreads();
            // parallel readback: 256 threads fetch one double each (LLC), sum in LDS
            if (threadIdx.x < 256)
                ndls[threadIdx.x] = LD_RLX(&NDB[step * 256 + threadIdx.x]);
            __syncthreads();
            if (threadIdx.x < 8){
                double n_ = 0.0, d_ = 0.0;
                #pragma unroll
                for (int bk = 0; bk < ND_BANKS; bk++){
                    n_ += ndls[bk * 16 + threadIdx.x];
                    d_ += ndls[bk * 16 + 8 + threadIdx.x];
                }
                double v = n_ / d_;
                om_s[threadIdx.x] = v;
                if (blockIdx.x == 0)                       // omega history (steps 0..17)
                    ST_RLX(&OHIST[step * 8 + threadIdx.x], v);
            }
            __syncthreads();
        }
    }
    #pragma unroll
    for (int k = 0; k < 8; k++) U[k * NPAIR + tid] = make_float2(urx[k], ury[k]);
}

// ===== kernel 2 (R30/R31): fused stageC+D + outputs =====
// stageCD (R21/R24 real packs) writes slices; release fence; 128-block barrier
// (CNT2, 8 groups); acquire fence; outs phase: each block does out0 tiles
// {2bx, 2bx+1}, out1 tile bx; block 0 also omega. omsm overlaid INSIDE dynamic
// LDS (R31 fix: static+64KB dynamic exceeded the launch envelope).
__global__ __launch_bounds__(1024) void k_cd_outs(float2* __restrict__ U,
                                                  double* __restrict__ Dbase,
                                                  float* __restrict__ out){
    extern __shared__ float2 lds[];
    int tid = threadIdx.x;
    int bx = blockIdx.x;                     // b = k*16 + cw
    int*    CNT2  = (int*)(Dbase + D_CNT2);
    const double* NDB   = Dbase + D_NDB;
    const double* OHIST = Dbase + D_OHIST;
    const float2* pos = U + bx * 8192;
    float* slice = (float*)(U) + (size_t)bx * 16384;
    const float inv = 1.0f / 16384.0f;
    // build G[p]
    #pragma unroll
    for (int r = 0; r < 8; r++){
        int p = r * 1024 + tid;
        float2 Hk, HkM;
        if (p == 0){
            Hk  = make_float2(pos[0].x, 0.f);
            HkM = make_float2(pos[8191].x, 0.f);
        } else {
            Hk = pos[p];
            float2 q2 = pos[8192 - p];
            HkM = make_float2(q2.x, -q2.y);
        }
        float2 S  = cadd(Hk, HkM);
        float2 Dv = csub(Hk, HkM);
        float sn, cn;
        sincospif((float)p / 8192.0f, &sn, &cn);     // W^p = e^{+i pi p/8192}
        float2 c = cmul(make_float2(cn, sn), Dv);
        lds[SW(p)] = make_float2(S.x - c.y, S.y + c.x);   // S + i*c
    }
    __syncthreads();
    lds_fft8192_r8<1>(lds, tid);
    // z[n] -> slice (n in [2048,6144)); zreg doubles as the forward-pack input w
    float2 zreg[4];
    #pragma unroll
    for (int q = 2; q < 6; q++){
        int n = q * 1024 + tid;
        float2 z = lds[SW(n)];
        zreg[q - 2] = make_float2(z.x * inv, z.y * inv);
        *(float2*)&slice[2 * n - 4096] = zreg[q - 2];     // coalesced 8B store
    }
    __syncthreads();
    // w[i] = z[2048+i]; thread holds i = tid, 1024+tid, 2048+tid, 3072+tid
    #pragma unroll
    for (int q = 0; q < 4; q++)
        lds[SW(q * 1024 + tid)] = zreg[q];
    __syncthreads();
    lds_fft4096_r8<-1>(lds, tid);
    // unpack Re(Y) and write both mirror halves
    #pragma unroll
    for (int q = 0; q < 4; q++){
        int k = q * 1024 + tid;
        float2 Wk = lds[SW(k)];
        float2 Wm = lds[SW((4096 - k) & 4095)];
        float ax = 0.5f * (Wk.x + Wm.x);                  // Re(A), Wc = conj(Wm)
        float dx = Wk.x - Wm.x, dy = Wk.y + Wm.y;         // d = Wk - conj(Wm)
        float bx2 = 0.5f * dy, by = -0.5f * dx;           // B = d/(2i)
        float sn, cn;
        sincospif(-(float)k / 4096.0f, &sn, &cn);         // e^{-i pi k/4096}
        float rey = ax + cn * bx2 - sn * by;
        slice[12288 + k] = rey;                           // t = k+4096
        if (k > 0) slice[12288 - k] = rey;                // t = 4096-k (mirror)
        else       slice[8192]      = Wk.x - Wk.y;        // t = 0: Re(Y[4096])
    }
    // ---- publish slices, barrier, acquire ----
    __syncthreads();                         // all waves' stores issued
    __threadfence();                         // release: writeback -> durable at LLC
    __syncthreads();
    if (tid == 0) gbar(CNT2, bx >> 4, 1, 8); // 128 blocks, 8 groups of 16
    __syncthreads();
    __threadfence();                         // acquire: invalidate stale L1/L2
    __syncthreads();

    // ---- outs phase ----
    const float* U32 = (const float*)U;
    float* fl = (float*)lds;
    // out0 tiles ti = 2bx, 2bx+1: out0[(k*8192+t)*16+ch] = y[k*16+cw][t], ch=(cw+8)&15
    float (*tile0)[257] = (float(*)[257])fl;              // 16448 B
    #pragma unroll
    for (int ti2 = 0; ti2 < 2; ti2++){
        int ti = 2 * bx + ti2;
        int k  = ti >> 5;
        int t0 = (ti & 31) * 256;
        #pragma unroll
        for (int i = 0; i < 4; i++){
            int idx = i * 1024 + tid;
            int cw = idx >> 8, dt = idx & 255;
            tile0[cw][dt] = U32[((size_t)(k * 16 + cw)) * 16384 + t0 + dt];
        }
        __syncthreads();
        #pragma unroll
        for (int i = 0; i < 4; i++){
            int f = i * 1024 + tid;          // f = dt*16 + ch
            int dt = f >> 4, ch = f & 15;
            int cw = (ch + 8) & 15;
            out[(size_t)k * 131072 + t0 * 16 + f] = tile0[cw][dt];
        }
        __syncthreads();
    }
    // out1 tile bx: out1[1048576 + t*128 + b] = W2[b][t], t0 = bx*64
    {
        float (*tile1)[65] = (float(*)[65])fl;            // 33280 B
        int t0 = bx * 64;
        #pragma unroll
        for (int i = 0; i < 8; i++){
            int idx = i * 1024 + tid;
            int b = idx >> 6, dt = idx & 63;
            tile1[b][dt] = U32[(size_t)b * 16384 + 8192 + t0 + dt];
        }
        __syncthreads();
        #pragma unroll
        for (int i = 0; i < 8; i++){
            int f = i * 1024 + tid;
            int dt = f >> 7, b = f & 127;
            out[1048576 + (size_t)(t0 + dt) * 128 + b] = tile1[b][dt];
        }
    }
    // omega history: rows 1..18 from OHIST; row 19 folded from NDB[18]; row 0 const
    if (bx == 0){
        double* omsm = (double*)((char*)lds + 40960);     // overlay, disjoint of tile1
        if (tid < 256) omsm[tid] = NDB[18 * 256 + tid];
        __syncthreads();
        if (tid < 8){
            double n_ = 0.0, d_ = 0.0;
            #pragma unroll
            for (int bk = 0; bk < ND_BANKS; bk++){
                n_ += omsm[bk * 16 + tid];
                d_ += omsm[bk * 16 + 8 + tid];
            }
            omsm[256 + tid] = n_ / d_;
        }
        __syncthreads();
        if (tid < 160){
            int row = tid >> 3, k = tid & 7;
            double v;
            if (row == 0)       v = 0.0625 * (double)k;
            else if (row <= 18) v = OHIST[(row - 1) * 8 + k];
            else                v = omsm[256 + k];
            out[2097152 + tid] = (float)v;
        }
    }
}

extern "C" void kernel_launch(void* const* d_in, const int* in_sizes, int n_in,
                              void* d_out, int out_size, void* d_ws, size_t ws_size,
                              hipStream_t stream){
    const float* sig = (const float*)d_in[0];
    float* out = (float*)d_out;
    char* p = (char*)d_ws;
    // ws: U 8 MB (C[64][4096] aliases its first 2 MB — dead before U is written) |
    //     D (NDB + CNT + OHIST + CNT2 ~47KB) at p+8MB => ~8.05 MB footprint
    float2* U = (float2*)p;
    float2* C = (float2*)p;                                  // alias U[0 .. 2MB)
    double* D = (double*)(p + (size_t)8 * 1024 * 1024);

    hipMemsetAsync(D, 0, D_ZERO * sizeof(double), stream);   // NDB+CNT+OHIST+CNT2
    k_vmd_all<<<dim3(VMD_BLOCKS), dim3(512), 32768, stream>>>(sig, C, U, D);
    k_cd_outs<<<dim3(128), dim3(1024), 65536, stream>>>(U, D, out);
}

// Round 16
// 150.437 us; speedup vs baseline: 1.6752x; 1.6752x over previous
//
#include <hip/hip_runtime.h>
#include <math.h>

#define NPAIR 131072          // 8192 freqs x 16 channels
#define STEPS 19
#define VMD_BLOCKS 256        // x 512 threads = NPAIR
#define ND_BANKS 16

// XOR swizzle: spreads strided radix-8 writes across banks; keeps contiguous free
#define SW(a) ((a) ^ (((a) >> 5) & 31))

#define LD_RLX(p)    __hip_atomic_load((p),       __ATOMIC_RELAXED, __HIP_MEMORY_SCOPE_AGENT)
#define ST_RLX(p,v)  __hip_atomic_store((p),(v),  __ATOMIC_RELAXED, __HIP_MEMORY_SCOPE_AGENT)
#define FAA_RLX(p,v) __hip_atomic_fetch_add((p),(v),__ATOMIC_RELAXED, __HIP_MEMORY_SCOPE_AGENT)

// D-region layout (doubles):
//   NDB[19][256] = [0, 4864) | CNT ints at [4864, 5400) (1057 ints used, fits) |
//   OHIST[18][8] at [5400, 5544). Zero [0,5400); OHIST is store-only.
// SESSION LESSONS (final):
//  - R28: bulk arrays via per-element agent-scope atomics = op-rate-bound (+22us).
//  - R31: bulk via cached stores + __threadfence release/acquire = WORSE
//    (+46us vmd, +100us CD) — fence maintenance serializes chip-wide.
//  - VERDICT: kernel boundary is the cheapest bulk-visibility mechanism here.
//    LLC atomics are for control words + in-LLC reduction (NDB) ONLY.
#define D_NDB   0
#define D_CNT   4864
#define D_OHIST 5400

__device__ __forceinline__ float2 cadd(float2 a, float2 b){ return make_float2(a.x+b.x, a.y+b.y); }
__device__ __forceinline__ float2 csub(float2 a, float2 b){ return make_float2(a.x-b.x, a.y-b.y); }
__device__ __forceinline__ float2 cmul(float2 a, float2 b){
    return make_float2(a.x*b.x - a.y*b.y, a.x*b.y + a.y*b.x);
}
template<int SGN>
__device__ __forceinline__ float2 imul(float2 a){   // multiply by e^{SGN*i*pi/2}
    return (SGN > 0) ? make_float2(-a.y, a.x) : make_float2(a.y, -a.x);
}

// 8-point DFT: y_k = sum_r a_r e^{SGN*2pi i r k/8}
template<int SGN>
__device__ __forceinline__ void dft8(const float2* a, float2* y){
    const float C = 0.70710678118654752f;
    const float sg = (SGN > 0) ? 1.f : -1.f;
    float2 t0 = cadd(a[0], a[4]), t1 = csub(a[0], a[4]);
    float2 t2 = cadd(a[2], a[6]), t3 = imul<SGN>(csub(a[2], a[6]));
    float2 E0 = cadd(t0, t2), E2 = csub(t0, t2), E1 = cadd(t1, t3), E3 = csub(t1, t3);
    float2 s0 = cadd(a[1], a[5]), s1 = csub(a[1], a[5]);
    float2 s2 = cadd(a[3], a[7]), s3 = imul<SGN>(csub(a[3], a[7]));
    float2 O0 = cadd(s0, s2), O2 = csub(s0, s2), O1 = cadd(s1, s3), O3 = csub(s1, s3);
    float2 w1 = make_float2(C, sg * C), w3 = make_float2(-C, sg * C);
    float2 R0 = O0, R1 = cmul(O1, w1), R2 = imul<SGN>(O2), R3 = cmul(O3, w3);
    y[0] = cadd(E0, R0); y[4] = csub(E0, R0);
    y[1] = cadd(E1, R1); y[5] = csub(E1, R1);
    y[2] = cadd(E2, R2); y[6] = csub(E2, R2);
    y[3] = cadd(E3, R3); y[7] = csub(E3, R3);
}

// ===== in-LDS 8192-pt Stockham FFT: 4 radix-8 passes + 1 radix-2, 1024 threads =====
template<int SGN>
__device__ void lds_fft8192_r8(float2* lds, int tid){
    #pragma unroll
    for (int pi = 0; pi < 4; pi++){
        int ls = 3 * pi;
        int s  = 1 << ls;
        int nn = 8192 >> ls;
        int q = tid & (s - 1);
        float2 a[8], y[8];
        #pragma unroll
        for (int r = 0; r < 8; r++) a[r] = lds[SW(tid + (r << 10))];
        __syncthreads();
        dft8<SGN>(a, y);
        int p = tid >> ls;
        float ang = (float)(2 * p) / (float)nn;
        float sn, cs;
        sincospif(SGN > 0 ? ang : -ang, &sn, &cs);   // w = e^{SGN*2pi i p/nn}
        float2 w = make_float2(cs, sn);
        float2 wk = make_float2(1.f, 0.f);
        int o = q + ((tid - q) << 3);                 // q + 8*s*p
        lds[SW(o)] = y[0];
        #pragma unroll
        for (int k = 1; k < 8; k++){
            wk = cmul(wk, w);
            lds[SW(o + (k << ls))] = cmul(y[k], wk);
        }
        __syncthreads();
    }
    #pragma unroll
    for (int w4 = 0; w4 < 4; w4++){                   // final radix-2, twiddle-free
        int idx = (w4 << 10) + tid;
        float2 a = lds[SW(idx)], b = lds[SW(idx + 4096)];
        lds[SW(idx)]        = cadd(a, b);
        lds[SW(idx + 4096)] = csub(a, b);
    }
    __syncthreads();
}

// ===== in-LDS 4096-pt Stockham FFT: exactly 4 radix-8 passes, 512 active threads ====
template<int SGN>
__device__ void lds_fft4096_r8(float2* lds, int tid){
    #pragma unroll
    for (int pi = 0; pi < 4; pi++){
        int ls = 3 * pi;
        int s  = 1 << ls;
        int nn = 4096 >> ls;
        float2 a[8], y[8];
        int q = tid & (s - 1);
        if (tid < 512){
            #pragma unroll
            for (int r = 0; r < 8; r++) a[r] = lds[SW(tid + (r << 9))];
        }
        __syncthreads();
        if (tid < 512){
            dft8<SGN>(a, y);
            int p = tid >> ls;
            float ang = (float)(2 * p) / (float)nn;
            float sn, cs;
            sincospif(SGN > 0 ? ang : -ang, &sn, &cs);
            float2 w = make_float2(cs, sn);
            float2 wk = make_float2(1.f, 0.f);
            int o = q + ((tid - q) << 3);
            lds[SW(o)] = y[0];
            #pragma unroll
            for (int k = 1; k < 8; k++){
                wk = cmul(wk, w);
                lds[SW(o + (k << ls))] = cmul(y[k], wk);
            }
        }
        __syncthreads();
    }
}

// ===== stage A (R26): 4-way DIT — 64 blocks x FFT4096 =====
// FFT16384 = sum_r W16384^{jr} C_r[j mod 4096], C_r = FFT4096 of x[4n+r].
// 4-term combine fused into k_vmd_all's load. C aliases U's first 2 MB (dead
// before U written). Zero-fill of NDB+CNT fused here (kernel boundary orders it).
__global__ __launch_bounds__(512) void k_stageA(const float* __restrict__ sig,
                                                float2* __restrict__ C,
                                                double* __restrict__ D){
    extern __shared__ float2 lds[];
    int tid = threadIdx.x;
    int bb  = blockIdx.x;                    // bb = cw*4 + r4
    int zi = bb * 512 + tid;                 // 64*512 = 32768 threads cover 5400
    if (zi < 5400) D[zi] = 0.0;
    int cw = bb >> 2, r4 = bb & 3;
    int cs = (cw + 8) & 15;                  // fftshift over channel axis
    const float* sp = sig + cs * 8192;
    #pragma unroll
    for (int i = 0; i < 8; i++){             // samples 4p+r4 of mirrored extension
        int p = i * 512 + tid;
        int x = 4 * p + r4;
        int mx = (x < 4096) ? (4095 - x) : ((x < 12288) ? (x - 4096) : (20479 - x));
        lds[SW(p)] = make_float2(sp[mx], 0.f);
    }
    __syncthreads();
    lds_fft4096_r8<-1>(lds, tid);
    float2* dst = C + (size_t)bb * 4096;
    #pragma unroll
    for (int i = 0; i < 8; i++){
        int j = i * 512 + tid;
        dst[j] = lds[SW(j)];
    }
}

// ===== fused 19-step VMD: R23 barrier + R27 f32 + R32 barrier micro-opts ====
// R17 reduce; R23 rcp; R25 banked-atomicAdd in-LLC aggregation; R27 f32 path.
// R32: (1) busy-spin poll (no s_sleep — detection is poll-quantum-bound, flag
// lines have <=16 pure readers); (2) compressed readback — 8 threads fold 32
// LLC loads each directly (same bk order -> bitwise-identical omega), dropping
// one __syncthreads + the LDS staging per step.
__global__ __launch_bounds__(512, 2) void k_vmd_all(const float2* __restrict__ C,
                                                    float2* __restrict__ U,
                                                    double* __restrict__ D){
    double* NDB   = D + D_NDB;
    int*    CNT   = (int*)(D + D_CNT);
    double* OHIST = D + D_OHIST;

    int tid = blockIdx.x * 512 + threadIdx.x;   // [0,NPAIR), tid = cw*8192+j
    int j = tid & 8191;
    int cw = tid >> 13;
    float fr = (float)j / 16384.0f;             // exact (j < 8192, pow2 divide)
    // R26 4-way combine: F[j] = C0 + w*C1 + w^2*C2 + w^3*C3, w = e^{-i pi j/8192}
    const float2* Cb = C + (size_t)(cw * 4) * 4096;
    int m = j & 4095;
    float2 C0 = Cb[m], C1 = Cb[4096 + m], C2 = Cb[8192 + m], C3 = Cb[12288 + m];
    float s1, c1, s2, c2;
    sincospif(-(float)j / 8192.0f, &s1, &c1);
    sincospif(-(float)j / 4096.0f, &s2, &c2);
    float2 w1 = make_float2(c1, s1), w2 = make_float2(c2, s2), w3 = cmul(w1, w2);
    float2 fv = cadd(cadd(C0, cmul(w1, C1)), cadd(cmul(w2, C2), cmul(w3, C3)));
    float fx = fv.x, fy = fv.y;
    float urx[8], ury[8], om[8];
    #pragma unroll
    for (int k = 0; k < 8; k++){ urx[k] = 0.f; ury[k] = 0.f; om[k] = 0.0625f * (float)k; }
    __shared__ float  lred[8][16];
    __shared__ double om_s[8];
    int lane = threadIdx.x & 63, wv = threadIdx.x >> 6;
    int mybank = (blockIdx.x & (ND_BANKS - 1)) * 16;
    int grp = blockIdx.x >> 4;                  // 16 groups of 16 blocks

    for (int step = 0; step < STEPS; step++){
        if (step > 0){
            #pragma unroll
            for (int k = 0; k < 8; k++) om[k] = (float)om_s[k];  // replicate astype(c64)
        }
        float sx = 0.f, sy = 0.f;
        #pragma unroll
        for (int k = 1; k < 8; k++){ sx += urx[k]; sy += ury[k]; }
        float lx = 0.f, ly = 0.f, nloc[8], dloc[8];
        #pragma unroll
        for (int k = 0; k < 8; k++){
            if (k > 0){ sx += lx - urx[k]; sy += ly - ury[k]; }
            float d = fr - om[k];
            float den = 1.0f + 2000.0f * d * d;
            float rden = 1.0f / den;                  // R23: 1 div + 2 mul
            float nx = (fx - sx) * rden, ny = (fy - sy) * rden;
            urx[k] = nx; ury[k] = ny;
            lx = nx; ly = ny;
            float pw = nx * nx + ny * ny;
            nloc[k] = fr * pw; dloc[k] = pw;
        }
        // ---- multi-value butterfly reduce: 16 floats across 64 lanes, 17 shuffles ----
        float s8[8];
        {
            bool hi = (lane & 32) != 0;
            #pragma unroll
            for (int k = 0; k < 8; k++){
                float t = hi ? nloc[k] : dloc[k];           // what we give away
                float r = __shfl_xor(t, 32);
                s8[k] = (hi ? dloc[k] : nloc[k]) + r;       // what we keep
            }
        }
        float s4v[4];
        {
            bool hi = (lane & 16) != 0;
            #pragma unroll
            for (int k = 0; k < 4; k++){
                float t = hi ? s8[k] : s8[k + 4];
                float r = __shfl_xor(t, 16);
                s4v[k] = (hi ? s8[k + 4] : s8[k]) + r;
            }
        }
        float s2v[2];
        {
            bool hi = (lane & 8) != 0;
            #pragma unroll
            for (int k = 0; k < 2; k++){
                float t = hi ? s4v[k] : s4v[k + 2];
                float r = __shfl_xor(t, 8);
                s2v[k] = (hi ? s4v[k + 2] : s4v[k]) + r;
            }
        }
        float sv;
        {
            bool hi = (lane & 4) != 0;
            float t = hi ? s2v[0] : s2v[1];
            float r = __shfl_xor(t, 4);
            sv = (hi ? s2v[1] : s2v[0]) + r;
        }
        sv += __shfl_xor(sv, 2);
        sv += __shfl_xor(sv, 1);
        // lane l holds wave-total for idx = l>>2 (idx<8: n_idx, idx>=8: d_{idx-8})
        if ((lane & 3) == 0) lred[wv][lane >> 2] = sv;
        __syncthreads();
        if (threadIdx.x < 16){
            double sum = 0.0;
            #pragma unroll
            for (int w = 0; w < 8; w++) sum += (double)lred[w][threadIdx.x];
            atomicAdd(&NDB[step * 256 + mybank + threadIdx.x], sum);  // LLC f64 atomic
        }
        __syncthreads();      // all waves vmcnt-drained -> NDB adds COMPLETE at LLC
        if (step < STEPS - 1){
            if (threadIdx.x == 0){
                int target = 16 * (step + 1);   // monotonic counters: no reset race
                int old = FAA_RLX(&CNT[grp * 32], 1);
                bool released = false;
                if (old == target - 1){         // group-last: bump root counter
                    int rold = FAA_RLX(&CNT[512], 1);
                    if (rold == target - 1){    // root-last: broadcast ALL group flags
                        #pragma unroll
                        for (int g = 0; g < 16; g++)
                            ST_RLX(&CNT[576 + g * 32], step + 1);
                        released = true;        // root-last proceeds immediately
                    }
                }
                if (!released)
                    while (LD_RLX(&CNT[576 + grp * 32]) <= step) { }  // R32 busy spin
            }
            __syncthreads();
            // R32 compressed readback: 8 threads fold 32 LLC loads each directly
            if (threadIdx.x < 8){
                const double* row = &NDB[step * 256];
                double n_ = 0.0, d_ = 0.0;
                #pragma unroll
                for (int bk = 0; bk < ND_BANKS; bk++){
                    n_ += LD_RLX(&row[bk * 16 + threadIdx.x]);
                    d_ += LD_RLX(&row[bk * 16 + 8 + threadIdx.x]);
                }
                double v = n_ / d_;
                om_s[threadIdx.x] = v;
                if (blockIdx.x == 0)                       // omega history (steps 0..17)
                    ST_RLX(&OHIST[step * 8 + threadIdx.x], v);
            }
            __syncthreads();
        }
    }
    #pragma unroll
    for (int k = 0; k < 8; k++) U[k * NPAIR + tid] = make_float2(urx[k], ury[k]);
}

// ===== stage C+D: real-iFFT pack (R21) + real-forward pack (R24) =====
// iFFT16384 of hermitian H via ONE complex FFT8192:
//   G[k] = (H[k]+H[k+M]) + i*W^k*(H[k]-H[k+M]), W=e^{+i pi k/8192}, M=8192
//   z = iFFT8192(G)/N -> y[2n]=Re z[n], y[2n+1]=Im z[n]; slice = y[4096..12287]
// Forward FFT8192 of the real slice via ONE FFT4096: pack input
//   w[i] = y_sl[2i] + i*y_sl[2i+1] = z[2048+i]  — exactly zreg, no refill.
//   W = FFT4096(w); Y[k] = A + e^{-i pi k/4096} B; Re(Y[8192-k]) = Re(Y[k]).
// After: U32[b*16384+t] = y_sl[t]; U32[b*16384+8192+t] = Re(Y[(t+4096)%8192])
__global__ __launch_bounds__(1024) void k_stageCD(float2* __restrict__ U){
    extern __shared__ float2 lds[];
    int tid = threadIdx.x;
    int b = blockIdx.x;                      // b = k*16 + cw
    const float2* pos = U + b * 8192;
    float* slice = (float*)(U) + (size_t)b * 16384;
    const float inv = 1.0f / 16384.0f;
    // build G[p]
    #pragma unroll
    for (int r = 0; r < 8; r++){
        int p = r * 1024 + tid;
        float2 Hk, HkM;
        if (p == 0){
            Hk  = make_float2(pos[0].x, 0.f);
            HkM = make_float2(pos[8191].x, 0.f);
        } else {
            Hk = pos[p];
            float2 q2 = pos[8192 - p];
            HkM = make_float2(q2.x, -q2.y);
        }
        float2 S  = cadd(Hk, HkM);
        float2 Dv = csub(Hk, HkM);
        float sn, cn;
        sincospif((float)p / 8192.0f, &sn, &cn);     // W^p = e^{+i pi p/8192}
        float2 c = cmul(make_float2(cn, sn), Dv);
        lds[SW(p)] = make_float2(S.x - c.y, S.y + c.x);   // S + i*c
    }
    __syncthreads();
    lds_fft8192_r8<1>(lds, tid);
    // z[n] -> slice (n in [2048,6144)); zreg doubles as the forward-pack input w
    float2 zreg[4];
    #pragma unroll
    for (int q = 2; q < 6; q++){
        int n = q * 1024 + tid;
        float2 z = lds[SW(n)];
        zreg[q - 2] = make_float2(z.x * inv, z.y * inv);
        *(float2*)&slice[2 * n - 4096] = zreg[q - 2];     // coalesced 8B store
    }
    __syncthreads();
    // w[i] = z[2048+i]; thread holds i = tid, 1024+tid, 2048+tid, 3072+tid
    #pragma unroll
    for (int q = 0; q < 4; q++)
        lds[SW(q * 1024 + tid)] = zreg[q];
    __syncthreads();
    lds_fft4096_r8<-1>(lds, tid);
    // unpack Re(Y) and write both mirror halves
    #pragma unroll
    for (int q = 0; q < 4; q++){
        int k = q * 1024 + tid;
        float2 Wk = lds[SW(k)];
        float2 Wm = lds[SW((4096 - k) & 4095)];
        float ax = 0.5f * (Wk.x + Wm.x);                  // Re(A), Wc = conj(Wm)
        float dx = Wk.x - Wm.x, dy = Wk.y + Wm.y;         // d = Wk - conj(Wm)
        float bx = 0.5f * dy, by = -0.5f * dx;            // B = d/(2i)
        float sn, cn;
        sincospif(-(float)k / 4096.0f, &sn, &cn);         // e^{-i pi k/4096}
        float rey = ax + cn * bx - sn * by;
        slice[12288 + k] = rey;                           // t = k+4096
        if (k > 0) slice[12288 - k] = rey;                // t = 4096-k (mirror)
        else       slice[8192]      = Wk.x - Wk.y;        // t = 0: Re(Y[4096])
    }
}

// ===== fused outputs: out0T (bx<256) | out1T (256<=bx<384) | omega (bx==384) ==
__global__ __launch_bounds__(256) void k_outs(const float* __restrict__ U32,
                                              const double* __restrict__ Dbase,
                                              float* __restrict__ out){
    __shared__ double smemd[128 * 65 / 2 + 140];
    float* smem = (float*)smemd;
    int bx = blockIdx.x;
    int tid = threadIdx.x;
    if (bx < 256){
        // out0[(k*8192+t)*16 + ch] = y[k*16+cw][t], ch=(cw+8)&15
        float (*tile)[257] = (float(*)[257])smem;
        int k  = bx >> 5;
        int t0 = (bx & 31) * 256;
        #pragma unroll
        for (int cw = 0; cw < 16; cw++)
            tile[cw][tid] = U32[((size_t)(k * 16 + cw)) * 16384 + t0 + tid];
        __syncthreads();
        #pragma unroll
        for (int i = 0; i < 16; i++){
            int flat = i * 256 + tid;        // flat = dt*16 + ch
            int dt = flat >> 4, ch = flat & 15;
            int cw = (ch + 8) & 15;
            out[(size_t)k * 131072 + t0 * 16 + flat] = tile[cw][dt];
        }
    } else if (bx < 384){
        // out1[1048576 + t*128 + b] = W2[b][t]
        float (*tile)[65] = (float(*)[65])smem;
        int t0 = (bx - 256) * 64;
        #pragma unroll
        for (int i = 0; i < 32; i++){
            int flat = i * 256 + tid;
            int b = flat >> 6, dt = flat & 63;
            tile[b][dt] = U32[(size_t)b * 16384 + 8192 + t0 + dt];
        }
        __syncthreads();
        #pragma unroll
        for (int i = 0; i < 32; i++){
            int flat = i * 256 + tid;
            int dt = flat >> 7, b = flat & 127;
            out[1048576 + (size_t)(t0 + dt) * 128 + b] = tile[b][dt];
        }
    } else {
        // omega history: rows 1..18 from OHIST; row 19 folded from NDB[18]; row 0 const
        const double* NDB   = Dbase + D_NDB;
        const double* OHIST = Dbase + D_OHIST;
        double* dsm = smemd;
        if (tid < 256) dsm[tid] = NDB[18 * 256 + tid];
        __syncthreads();
        if (tid < 8){
            double n_ = 0.0, d_ = 0.0;
            #pragma unroll
            for (int bk = 0; bk < ND_BANKS; bk++){
                n_ += dsm[bk * 16 + tid];
                d_ += dsm[bk * 16 + 8 + tid];
            }
            dsm[256 + tid] = n_ / d_;
        }
        __syncthreads();
        if (tid < 160){
            int row = tid >> 3, k = tid & 7;
            double v;
            if (row == 0)       v = 0.0625 * (double)k;
            else if (row <= 18) v = OHIST[(row - 1) * 8 + k];
            else                v = dsm[256 + k];
            out[2097152 + tid] = (float)v;
        }
    }
}

extern "C" void kernel_launch(void* const* d_in, const int* in_sizes, int n_in,
                              void* d_out, int out_size, void* d_ws, size_t ws_size,
                              hipStream_t stream){
    const float* sig = (const float*)d_in[0];
    float* out = (float*)d_out;
    char* p = (char*)d_ws;
    // ws: U 8 MB (C[64][4096] aliases its first 2 MB — dead before U is written) |
    //     D (NDB 38KB + CNT 4.3KB + OHIST 1.2KB) at p+8MB => ~8.05 MB footprint
    float2* U = (float2*)p;
    float2* C = (float2*)p;                                  // alias U[0 .. 2MB)
    double* D = (double*)(p + (size_t)8 * 1024 * 1024);

    k_stageA<<<dim3(64), dim3(512), 32768, stream>>>(sig, C, D);
    k_vmd_all<<<dim3(VMD_BLOCKS), dim3(512), 0, stream>>>(C, U, D);
    k_stageCD<<<dim3(128), dim3(1024), 65536, stream>>>(U);
    k_outs<<<dim3(385), dim3(256), 0, stream>>>((const float*)U, D, out);
}